// Round 14
// baseline (241.846 us; speedup 1.0000x reference)
//
#include <hip/hip_runtime.h>
#include <hip/hip_bf16.h>

// Problem constants
#define B_  32
#define T_  512
#define D_  512
#define HD_ 64
#define HN_ 16
#define O_  512
#define M_  (B_ * T_)      // 16384 rows
#define NQ_ (HN_ * HD_)    // 1024 qkv cols

typedef __bf16 bf16;
typedef __attribute__((ext_vector_type(8))) __bf16 bf16x8;
typedef __attribute__((ext_vector_type(4))) __bf16 bf16x4;
typedef __attribute__((ext_vector_type(4))) float f32x4;

static __device__ __forceinline__ f32x4 mfma16(bf16x8 a, bf16x8 b, f32x4 c) {
    return __builtin_amdgcn_mfma_f32_16x16x32_bf16(a, b, c, 0, 0, 0);
}

// Direct global->LDS 16B copy.
static __device__ __forceinline__ void load_lds_16B(const bf16* g, bf16* l) {
    __builtin_amdgcn_global_load_lds(
        (const __attribute__((address_space(1))) unsigned int*)(unsigned long long)g,
        (__attribute__((address_space(3))) unsigned int*)(unsigned long long)l,
        16, 0, 0);
}

static __device__ __forceinline__ float fast_tanh(float x) {
    return 1.f - 2.f / (__expf(2.f * x) + 1.f);
}

// T1 chunked XCD swizzle: requires (gridDim.x*gridDim.y) % 8 == 0.
static __device__ __forceinline__ int2 swz_block() {
    const int nx = gridDim.x;
    const int nwg = nx * gridDim.y;
    int l = blockIdx.y * nx + blockIdx.x;
    l = (l & 7) * (nwg >> 3) + (l >> 3);
    return make_int2(l % nx, l / nx);
}

// ---------------------------------------------------------------------------
// Fused prep: conv_input (4096 blocks) | headw (384) | plain (256) | bias (14).
// ---------------------------------------------------------------------------
__global__ __launch_bounds__(256) void prep_all_kernel(
    const float* __restrict__ inputs,
    const float* __restrict__ Wq, const float* __restrict__ Wk,
    const float* __restrict__ Wv, const float* __restrict__ Wr,
    const float* __restrict__ Wo, const float* __restrict__ Wfc,
    const float* __restrict__ bq, const float* __restrict__ bk,
    const float* __restrict__ bv, const float* __restrict__ br,
    bf16* __restrict__ xin, bf16* __restrict__ wall,
    bf16* __restrict__ wrt, bf16* __restrict__ wot, bf16* __restrict__ wfct,
    float* __restrict__ ball)
{
    __shared__ bf16 tl[64][72];
    const int tid = threadIdx.x;
    int id = blockIdx.x;

    if (id < 4096) {
        const size_t i = ((size_t)id * 256 + tid) * 8;
        f32x4 x0 = *(const f32x4*)(inputs + i);
        f32x4 x1 = *(const f32x4*)(inputs + i + 4);
        bf16x8 v;
        v[0] = (bf16)x0[0]; v[1] = (bf16)x0[1]; v[2] = (bf16)x0[2]; v[3] = (bf16)x0[3];
        v[4] = (bf16)x1[0]; v[5] = (bf16)x1[1]; v[6] = (bf16)x1[2]; v[7] = (bf16)x1[3];
        *(bf16x8*)(xin + i) = v;
        return;
    }
    if (id < 4480) {
        id -= 4096;
        const int kt = id & 7; id >>= 3;
        const int h = id & 15; id >>= 4;
        const float* src = (id == 0) ? Wq : (id == 1) ? Wk : Wv;
        bf16* dst = wall + (size_t)id * (1024 * 512);
        const int k0 = kt * 64;
#pragma unroll
        for (int i = 0; i < 4; i++) {
            const int e = i * 256 + tid;
            const int kk = e >> 4, f4 = (e & 15) * 4;
            const f32x4 v = *(const f32x4*)(src + ((size_t)h * 512 + k0 + kk) * 64 + f4);
#pragma unroll
            for (int j = 0; j < 4; j++) tl[f4 + j][kk] = (bf16)v[j];
        }
        __syncthreads();
#pragma unroll
        for (int i = 0; i < 2; i++) {
            const int e = i * 256 + tid;
            const int f = e >> 3, kc = (e & 7) * 8;
            *(bf16x8*)(dst + ((size_t)h * 64 + f) * 512 + k0 + kc) = *(const bf16x8*)&tl[f][kc];
        }
        return;
    }
    if (id < 4736) {
        id -= 4480;
        const float* src; bf16* dst; int K;
        if (id < 64)       { src = Wr;  dst = wrt;  K = 512;  }
        else if (id < 192) { src = Wo;  dst = wot;  K = 1024; id -= 64; }
        else               { src = Wfc; dst = wfct; K = 512;  id -= 192; }
        const int kt = id >> 3, nt = id & 7;
        const int k0 = kt * 64, n0 = nt * 64;
#pragma unroll
        for (int i = 0; i < 4; i++) {
            const int e = i * 256 + tid;
            const int kk = e >> 4, n4 = (e & 15) * 4;
            const f32x4 v = *(const f32x4*)(src + (size_t)(k0 + kk) * 512 + n0 + n4);
#pragma unroll
            for (int j = 0; j < 4; j++) tl[n4 + j][kk] = (bf16)v[j];
        }
        __syncthreads();
#pragma unroll
        for (int i = 0; i < 2; i++) {
            const int e = i * 256 + tid;
            const int nn = e >> 3, kc = (e & 7) * 8;
            *(bf16x8*)(dst + (size_t)(n0 + nn) * K + k0 + kc) = *(const bf16x8*)&tl[nn][kc];
        }
        return;
    }
    const int i = (id - 4736) * 256 + tid;  // 0..3583
    float v = (i < 1024) ? bq[i]
            : (i < 2048) ? bk[i - 1024]
            : (i < 3072) ? bv[i - 2048] : br[i - 3072];
    ball[i] = v;
}

// ---------------------------------------------------------------------------
// QKV+R GEMM, 256x256, BK=64, 8 waves, fine 4-phase counted-vmcnt
// (r9 champion schedule — frozen).  Region 3 (residual) now stores f32
// directly into d_out at final positions (block-local consumer in the fused
// LN kernel reads then overwrites the same rows -> race-free).
// ---------------------------------------------------------------------------
__global__ __launch_bounds__(512, 2) void gemm_qkvr256_kernel(
    const bf16* __restrict__ A, const bf16* __restrict__ Wall,
    const float* __restrict__ ball,
    bf16* __restrict__ qc, bf16* __restrict__ kb, bf16* __restrict__ vt,
    float* __restrict__ resf)
{
    __shared__ bf16 SL[65536];   // 128 KB
    const int tid = threadIdx.x;
    const int lane = tid & 63;
    const int w = tid >> 6;
    const int wm = w >> 2, wn = w & 3;
    const int lr = lane & 15, lg = lane >> 4;
    const int K = 512;

    const int2 bc = swz_block();
    const int m0 = bc.y * 256, n0 = bc.x * 256;

    const int p = tid & 7;
    const int rr = tid >> 3;
    const int g = p ^ (rr & 7);
    const int arow0 = rr, arow1 = 128 + rr;
    const int brow0 = ((rr >> 5) << 6) | (rr & 31);
    const int brow1 = 128 + brow0;

    auto STAGE_H = [&](int t, int h) {
        const int slot = t & 1;
        const int k0 = t << 6;
        if ((h & 1) == 0) {
            bf16* Bb = SL + 32768 + slot * 16384;
            const int off = (h == 2) ? 32 : 0;
            const int r0_ = brow0 + off, r1_ = brow1 + off;
            load_lds_16B(Wall + (size_t)(n0 + r0_) * K + k0 + g * 8, Bb + r0_ * 64 + p * 8);
            load_lds_16B(Wall + (size_t)(n0 + r1_) * K + k0 + g * 8, Bb + r1_ * 64 + p * 8);
        } else {
            bf16* Ab = SL + slot * 16384;
            const int off = (h == 3) ? 64 : 0;
            const int r0_ = arow0 + off, r1_ = arow1 + off;
            load_lds_16B(A + (size_t)(m0 + r0_) * K + k0 + g * 8, Ab + r0_ * 64 + p * 8);
            load_lds_16B(A + (size_t)(m0 + r1_) * K + k0 + g * 8, Ab + r1_ * 64 + p * 8);
        }
    };

    const int x = lr & 7;
    auto LDA = [&](int t, int mi, int kc) -> bf16x8 {
        const int row = wm * 128 + mi * 16 + lr;
        const bf16* Ab = SL + (t & 1) * 16384;
        return *(const bf16x8*)&Ab[row * 64 + ((((kc << 2) | lg) ^ x) << 3)];
    };
    auto LDB = [&](int t, int nj, int kc) -> bf16x8 {
        const int row = wn * 64 + nj * 16 + lr;
        const bf16* Bb = SL + 32768 + (t & 1) * 16384;
        return *(const bf16x8*)&Bb[row * 64 + ((((kc << 2) | lg) ^ x) << 3)];
    };

    f32x4 acc[8][4];
    const f32x4 zero4 = {0.f, 0.f, 0.f, 0.f};
#pragma unroll
    for (int i = 0; i < 8; i++)
#pragma unroll
        for (int j = 0; j < 4; j++) acc[i][j] = zero4;

    bf16x8 b01[4], b23[4], af[8];

    STAGE_H(0, 0); STAGE_H(0, 1); STAGE_H(0, 2); STAGE_H(0, 3);

    for (int t = 0; t < 7; t++) {
        asm volatile("s_waitcnt vmcnt(4)\n\ts_barrier" ::: "memory");
#pragma unroll
        for (int nj = 0; nj < 2; nj++)
#pragma unroll
            for (int kc = 0; kc < 2; kc++) b01[nj * 2 + kc] = LDB(t, nj, kc);
#pragma unroll
        for (int mi = 0; mi < 4; mi++)
#pragma unroll
            for (int kc = 0; kc < 2; kc++) af[mi * 2 + kc] = LDA(t, mi, kc);
        STAGE_H(t + 1, 0);
        __builtin_amdgcn_s_setprio(1);
#pragma unroll
        for (int mi = 0; mi < 4; mi++)
#pragma unroll
            for (int nj = 0; nj < 2; nj++)
#pragma unroll
                for (int kc = 0; kc < 2; kc++)
                    acc[mi][nj] = mfma16(af[mi * 2 + kc], b01[nj * 2 + kc], acc[mi][nj]);
        __builtin_amdgcn_s_setprio(0);
        asm volatile("s_waitcnt vmcnt(4)\n\ts_barrier" ::: "memory");
#pragma unroll
        for (int nj = 0; nj < 2; nj++)
#pragma unroll
            for (int kc = 0; kc < 2; kc++) b23[nj * 2 + kc] = LDB(t, nj + 2, kc);
        STAGE_H(t + 1, 1);
        __builtin_amdgcn_s_setprio(1);
#pragma unroll
        for (int mi = 0; mi < 4; mi++)
#pragma unroll
            for (int nj = 0; nj < 2; nj++)
#pragma unroll
                for (int kc = 0; kc < 2; kc++)
                    acc[mi][nj + 2] = mfma16(af[mi * 2 + kc], b23[nj * 2 + kc], acc[mi][nj + 2]);
        __builtin_amdgcn_s_setprio(0);
        asm volatile("s_waitcnt vmcnt(4)\n\ts_barrier" ::: "memory");
#pragma unroll
        for (int mi = 0; mi < 4; mi++)
#pragma unroll
            for (int kc = 0; kc < 2; kc++) af[mi * 2 + kc] = LDA(t, mi + 4, kc);
        STAGE_H(t + 1, 2);
        __builtin_amdgcn_s_setprio(1);
#pragma unroll
        for (int mi = 0; mi < 4; mi++)
#pragma unroll
            for (int nj = 0; nj < 2; nj++)
#pragma unroll
                for (int kc = 0; kc < 2; kc++)
                    acc[mi + 4][nj] = mfma16(af[mi * 2 + kc], b01[nj * 2 + kc], acc[mi + 4][nj]);
        __builtin_amdgcn_s_setprio(0);
        STAGE_H(t + 1, 3);
        __builtin_amdgcn_s_setprio(1);
#pragma unroll
        for (int mi = 0; mi < 4; mi++)
#pragma unroll
            for (int nj = 0; nj < 2; nj++)
#pragma unroll
                for (int kc = 0; kc < 2; kc++)
                    acc[mi + 4][nj + 2] = mfma16(af[mi * 2 + kc], b23[nj * 2 + kc], acc[mi + 4][nj + 2]);
        __builtin_amdgcn_s_setprio(0);
    }

    {
        const int t = 7;
        asm volatile("s_waitcnt vmcnt(4)\n\ts_barrier" ::: "memory");
#pragma unroll
        for (int nj = 0; nj < 2; nj++)
#pragma unroll
            for (int kc = 0; kc < 2; kc++) b01[nj * 2 + kc] = LDB(t, nj, kc);
#pragma unroll
        for (int mi = 0; mi < 4; mi++)
#pragma unroll
            for (int kc = 0; kc < 2; kc++) af[mi * 2 + kc] = LDA(t, mi, kc);
        __builtin_amdgcn_s_setprio(1);
#pragma unroll
        for (int mi = 0; mi < 4; mi++)
#pragma unroll
            for (int nj = 0; nj < 2; nj++)
#pragma unroll
                for (int kc = 0; kc < 2; kc++)
                    acc[mi][nj] = mfma16(af[mi * 2 + kc], b01[nj * 2 + kc], acc[mi][nj]);
        __builtin_amdgcn_s_setprio(0);
        asm volatile("s_waitcnt vmcnt(2)\n\ts_barrier" ::: "memory");
#pragma unroll
        for (int nj = 0; nj < 2; nj++)
#pragma unroll
            for (int kc = 0; kc < 2; kc++) b23[nj * 2 + kc] = LDB(t, nj + 2, kc);
        __builtin_amdgcn_s_setprio(1);
#pragma unroll
        for (int mi = 0; mi < 4; mi++)
#pragma unroll
            for (int nj = 0; nj < 2; nj++)
#pragma unroll
                for (int kc = 0; kc < 2; kc++)
                    acc[mi][nj + 2] = mfma16(af[mi * 2 + kc], b23[nj * 2 + kc], acc[mi][nj + 2]);
        __builtin_amdgcn_s_setprio(0);
        asm volatile("s_waitcnt vmcnt(0)\n\ts_barrier" ::: "memory");
#pragma unroll
        for (int mi = 0; mi < 4; mi++)
#pragma unroll
            for (int kc = 0; kc < 2; kc++) af[mi * 2 + kc] = LDA(t, mi + 4, kc);
        __builtin_amdgcn_s_setprio(1);
#pragma unroll
        for (int mi = 0; mi < 4; mi++)
#pragma unroll
            for (int nj = 0; nj < 2; nj++)
#pragma unroll
                for (int kc = 0; kc < 2; kc++)
                    acc[mi + 4][nj] = mfma16(af[mi * 2 + kc], b01[nj * 2 + kc], acc[mi + 4][nj]);
#pragma unroll
        for (int mi = 0; mi < 4; mi++)
#pragma unroll
            for (int nj = 0; nj < 2; nj++)
#pragma unroll
                for (int kc = 0; kc < 2; kc++)
                    acc[mi + 4][nj + 2] = mfma16(af[mi * 2 + kc], b23[nj * 2 + kc], acc[mi + 4][nj + 2]);
        __builtin_amdgcn_s_setprio(0);
    }
    __syncthreads();

    const int region = n0 >> 10;
    if (region == 2) {
#pragma unroll
        for (int mi = 0; mi < 8; mi++) {
#pragma unroll
            for (int nj = 0; nj < 4; nj++) {
                const int n = n0 + wn * 64 + nj * 16 + lr;
                const float bn = ball[n];
                const int m = m0 + wm * 128 + mi * 16 + lg * 4;
                const int bb = m >> 9, tt = m & 511;
                const int nn = n - 2048, hh = nn >> 6, f = nn & 63;
                bf16x4 st;
#pragma unroll
                for (int r = 0; r < 4; r++) st[r] = (bf16)fast_tanh(acc[mi][nj][r] + bn);
                *(bf16x4*)(vt + (((size_t)(bb * 16 + hh) * 64 + f) << 9) + tt) = st;
            }
        }
    } else if (region == 3) {
        // residual: f32 direct store into d_out at final row positions
#pragma unroll
        for (int mi = 0; mi < 8; mi++) {
#pragma unroll
            for (int nj = 0; nj < 4; nj++) {
                const int n = n0 + wn * 64 + nj * 16 + lr;
                const float bn = ball[n];
                const int nn = n - 3072;
#pragma unroll
                for (int r = 0; r < 4; r++) {
                    const int m = m0 + wm * 128 + mi * 16 + lg * 4 + r;
                    resf[(size_t)m * 512 + nn] = acc[mi][nj][r] + bn;
                }
            }
        }
    } else {
        bf16* dst; int nb; float scale = 1.f;
        if (region == 0) { dst = qc; nb = n0;        scale = 0.125f; }
        else             { dst = kb; nb = n0 - 1024; }
        float bn[4];
#pragma unroll
        for (int nj = 0; nj < 4; nj++) bn[nj] = ball[n0 + wn * 64 + nj * 16 + lr];
#pragma unroll
        for (int half = 0; half < 2; half++) {
            if (wm == half) {
#pragma unroll
                for (int mi = 0; mi < 8; mi++) {
#pragma unroll
                    for (int nj = 0; nj < 4; nj++) {
                        const int col = wn * 64 + nj * 16 + lr;
#pragma unroll
                        for (int r = 0; r < 4; r++) {
                            float v = fmaxf(acc[mi][nj][r] + bn[nj], 0.f);
                            SL[(mi * 16 + lg * 4 + r) * 264 + col] = (bf16)(v * scale);
                        }
                    }
                }
            }
            __syncthreads();
#pragma unroll
            for (int i = 0; i < 4; i++) {
                const int rr2 = i * 32 + (tid >> 4);
                const int cc = (tid & 15) * 16;
                bf16x8 v0 = *(const bf16x8*)&SL[rr2 * 264 + cc];
                bf16x8 v1 = *(const bf16x8*)&SL[rr2 * 264 + cc + 8];
                bf16* pdst = dst + (size_t)(m0 + half * 128 + rr2) * 1024 + nb + cc;
                *(bf16x8*)pdst = v0;
                *(bf16x8*)(pdst + 8) = v1;
            }
            __syncthreads();
        }
    }
}

// ---------------------------------------------------------------------------
// Fused tail: out = LN2( relu( LN1(tanh(qc@Wo+bo)+res) @ Wfc + bfc )
//                        + LN1(...) )
// One block = 64 rows x full 512 cols, 8 waves (wr=row-half, wn=col-quarter).
// Phase 1: r11 gemm_ln mainloop (A=qc K=1024, B=wot) -> LN1 tile kept in
//          LDS SLy [64][520] (never hits global).
// Phase 2: fc GEMM, A-frags from SLy (1040B stride -> 2-way banks, free),
//          B-frags direct from L2-resident wfct; LN2 -> f32 out.
// Partner (residual) is f32 in d_out rows m0..63: read before this block
// overwrites the same rows -> block-local, race-free.
// ---------------------------------------------------------------------------
__global__ __launch_bounds__(512) void gemm_ln_fused_kernel(
    const bf16* __restrict__ qc, const bf16* __restrict__ wot,
    const float* __restrict__ bo, const float* resf,
    const float* __restrict__ ln1w, const float* __restrict__ ln1b,
    const bf16* __restrict__ wfct, const float* __restrict__ bfc,
    const float* __restrict__ ln2w, const float* __restrict__ ln2b,
    float* outp)
{
    __shared__ bf16 SL[73728];          // ring: A 4x2048 @0, B 4x16384 @8192
    __shared__ float parts[2][4][64];
    bf16* SLp = SL;                     // 64x520 partner (dead-ring reuse)
    bf16* SLy = SL + 36864;             // 64x520 LN1 tile (dead-ring reuse)
    const int tid = threadIdx.x;
    const int lane = tid & 63;
    const int w = tid >> 6;
    const int wr = w >> 2, wn = w & 3;
    const int lr = lane & 15, lg = lane >> 4;
    const int m0 = blockIdx.x * 64;
    const int K1 = 1024;

    const int gs = (tid & 3) ^ ((tid >> 3) & 3);
    const bf16* aP = qc + (size_t)(m0 + (tid >> 2)) * K1 + gs * 8;
    const bf16* bP = wot + (size_t)(tid >> 2) * K1 + gs * 8;

    auto STAGE = [&](int t) {
        bf16* Ab = SL + (t & 3) * 2048;
        bf16* Bb = SL + 8192 + (t & 3) * 16384;
        const int k0 = t << 5;
        if (tid < 256) load_lds_16B(aP + k0, Ab + tid * 8);
#pragma unroll
        for (int j = 0; j < 4; j++)
            load_lds_16B(bP + k0 + (size_t)(j * 128) * K1, Bb + j * 4096 + tid * 8);
    };

    f32x4 acc[2][8];
    const f32x4 zero4 = {0.f, 0.f, 0.f, 0.f};
#pragma unroll
    for (int i = 0; i < 2; i++)
#pragma unroll
        for (int j = 0; j < 8; j++) acc[i][j] = zero4;

    STAGE(0); STAGE(1);
    if (w < 4) asm volatile("s_waitcnt vmcnt(5)" ::: "memory");
    else       asm volatile("s_waitcnt vmcnt(4)" ::: "memory");
    __builtin_amdgcn_s_barrier();

    for (int t = 0; t < 32; t++) {
        if (t + 2 < 32) {
            STAGE(t + 2);
            if (w < 4) asm volatile("s_waitcnt vmcnt(5)" ::: "memory");
            else       asm volatile("s_waitcnt vmcnt(4)" ::: "memory");
        } else {
            asm volatile("s_waitcnt vmcnt(0)" ::: "memory");
        }
        __builtin_amdgcn_s_barrier();

        const bf16* Ab = SL + (t & 3) * 2048;
        const bf16* Bb = SL + 8192 + (t & 3) * 16384;
        bf16x8 a[2], b[8];
#pragma unroll
        for (int mi = 0; mi < 2; mi++) {
            const int row = wr * 32 + mi * 16 + lr;
            a[mi] = *(const bf16x8*)&Ab[row * 32 + ((lg ^ ((row >> 1) & 3)) << 3)];
        }
#pragma unroll
        for (int nj = 0; nj < 8; nj++) {
            const int row = wn * 128 + nj * 16 + lr;
            b[nj] = *(const bf16x8*)&Bb[row * 32 + ((lg ^ ((row >> 1) & 3)) << 3)];
        }
        __builtin_amdgcn_s_setprio(1);
#pragma unroll
        for (int mi = 0; mi < 2; mi++)
#pragma unroll
            for (int nj = 0; nj < 8; nj++)
                acc[mi][nj] = mfma16(a[mi], b[nj], acc[mi][nj]);
        __builtin_amdgcn_s_setprio(0);
    }
    __syncthreads();

    // stage f32 partner (residual rows m0..63) -> SLp bf16 [64][520]
#pragma unroll
    for (int jj = 0; jj < 8; jj++) {
        const int e = jj * 512 + tid;
        const int row = e >> 6, col = (e & 63) * 8;
        const f32x4 u0 = *(const f32x4*)(resf + (size_t)(m0 + row) * 512 + col);
        const f32x4 u1 = *(const f32x4*)(resf + (size_t)(m0 + row) * 512 + col + 4);
        bf16x8 v;
#pragma unroll
        for (int q = 0; q < 4; q++) { v[q] = (bf16)u0[q]; v[4 + q] = (bf16)u1[q]; }
        *(bf16x8*)&SLp[row * 520 + col] = v;
    }
    __syncthreads();

    float lw[8], lb[8], bn[8];
#pragma unroll
    for (int nj = 0; nj < 8; nj++) {
        const int col = wn * 128 + nj * 16 + lr;
        bn[nj] = bo[col]; lw[nj] = ln1w[col]; lb[nj] = ln1b[col];
    }

    float rs[8], rq[8];
#pragma unroll
    for (int mi = 0; mi < 2; mi++)
#pragma unroll
        for (int r = 0; r < 4; r++) {
            const int row = wr * 32 + mi * 16 + lg * 4 + r;
            float ps = 0.f, pq = 0.f;
#pragma unroll
            for (int nj = 0; nj < 8; nj++) {
                float xv = fast_tanh(acc[mi][nj][r] + bn[nj]);
                xv += (float)SLp[row * 520 + wn * 128 + nj * 16 + lr];
                acc[mi][nj][r] = xv;
                ps += xv; pq += xv * xv;
            }
            rs[mi * 4 + r] = ps; rq[mi * 4 + r] = pq;
        }
#pragma unroll
    for (int i = 0; i < 8; i++) {
#pragma unroll
        for (int off = 1; off <= 8; off <<= 1) {
            rs[i] += __shfl_xor(rs[i], off);
            rq[i] += __shfl_xor(rq[i], off);
        }
    }
    if (lr == 0) {
#pragma unroll
        for (int mi = 0; mi < 2; mi++)
#pragma unroll
            for (int r = 0; r < 4; r++) {
                const int row = wr * 32 + mi * 16 + lg * 4 + r;
                parts[0][wn][row] = rs[mi * 4 + r];
                parts[1][wn][row] = rq[mi * 4 + r];
            }
    }
    __syncthreads();

    // LN1 -> SLy bf16 tile (stays in LDS)
#pragma unroll
    for (int mi = 0; mi < 2; mi++)
#pragma unroll
        for (int r = 0; r < 4; r++) {
            const int row = wr * 32 + mi * 16 + lg * 4 + r;
            const float S = parts[0][0][row] + parts[0][1][row] + parts[0][2][row] + parts[0][3][row];
            const float Q = parts[1][0][row] + parts[1][1][row] + parts[1][2][row] + parts[1][3][row];
            const float mm = S * (1.f / 512.f);
            const float iv = rsqrtf(Q * (1.f / 512.f) - mm * mm + 1e-5f);
#pragma unroll
            for (int nj = 0; nj < 8; nj++) {
                const int col = wn * 128 + nj * 16 + lr;
                SLy[row * 520 + col] = (bf16)((acc[mi][nj][r] - mm) * iv * lw[nj] + lb[nj]);
            }
        }
    __syncthreads();   // SLy complete; parts reads done -> reusable

    // ---- phase 2: fc GEMM (A from SLy, B direct from L2-resident wfct)
#pragma unroll
    for (int i = 0; i < 2; i++)
#pragma unroll
        for (int j = 0; j < 8; j++) acc[i][j] = zero4;

    for (int t2 = 0; t2 < 16; t2++) {
        bf16x8 a2[2], b2[8];
#pragma unroll
        for (int nj = 0; nj < 8; nj++)
            b2[nj] = *(const bf16x8*)(wfct + (size_t)(wn * 128 + nj * 16 + lr) * 512 + t2 * 32 + lg * 8);
#pragma unroll
        for (int mi = 0; mi < 2; mi++)
            a2[mi] = *(const bf16x8*)&SLy[(wr * 32 + mi * 16 + lr) * 520 + t2 * 32 + lg * 8];
        __builtin_amdgcn_s_setprio(1);
#pragma unroll
        for (int mi = 0; mi < 2; mi++)
#pragma unroll
            for (int nj = 0; nj < 8; nj++)
                acc[mi][nj] = mfma16(a2[mi], b2[nj], acc[mi][nj]);
        __builtin_amdgcn_s_setprio(0);
    }

#pragma unroll
    for (int nj = 0; nj < 8; nj++) {
        const int col = wn * 128 + nj * 16 + lr;
        bn[nj] = bfc[col]; lw[nj] = ln2w[col]; lb[nj] = ln2b[col];
    }

#pragma unroll
    for (int mi = 0; mi < 2; mi++)
#pragma unroll
        for (int r = 0; r < 4; r++) {
            const int row = wr * 32 + mi * 16 + lg * 4 + r;
            float ps = 0.f, pq = 0.f;
#pragma unroll
            for (int nj = 0; nj < 8; nj++) {
                float xv = fmaxf(acc[mi][nj][r] + bn[nj], 0.f);
                xv += (float)SLy[row * 520 + wn * 128 + nj * 16 + lr];
                acc[mi][nj][r] = xv;
                ps += xv; pq += xv * xv;
            }
            rs[mi * 4 + r] = ps; rq[mi * 4 + r] = pq;
        }
#pragma unroll
    for (int i = 0; i < 8; i++) {
#pragma unroll
        for (int off = 1; off <= 8; off <<= 1) {
            rs[i] += __shfl_xor(rs[i], off);
            rq[i] += __shfl_xor(rq[i], off);
        }
    }
    __syncthreads();   // ensure no wave still reads SLy before parts reuse? (parts only)
    if (lr == 0) {
#pragma unroll
        for (int mi = 0; mi < 2; mi++)
#pragma unroll
            for (int r = 0; r < 4; r++) {
                const int row = wr * 32 + mi * 16 + lg * 4 + r;
                parts[0][wn][row] = rs[mi * 4 + r];
                parts[1][wn][row] = rq[mi * 4 + r];
            }
    }
    __syncthreads();

#pragma unroll
    for (int mi = 0; mi < 2; mi++)
#pragma unroll
        for (int r = 0; r < 4; r++) {
            const int row = wr * 32 + mi * 16 + lg * 4 + r;
            const float S = parts[0][0][row] + parts[0][1][row] + parts[0][2][row] + parts[0][3][row];
            const float Q = parts[1][0][row] + parts[1][1][row] + parts[1][2][row] + parts[1][3][row];
            const float mm = S * (1.f / 512.f);
            const float iv = rsqrtf(Q * (1.f / 512.f) - mm * mm + 1e-5f);
#pragma unroll
            for (int nj = 0; nj < 8; nj++) {
                const int col = wn * 128 + nj * 16 + lr;
                outp[(size_t)(m0 + row) * 512 + col] =
                    (acc[mi][nj][r] - mm) * iv * lw[nj] + lb[nj];
            }
        }
}

// ---------------------------------------------------------------------------
// MFMA flash attention (r11 measured-best version, KVBLK=64).
// ---------------------------------------------------------------------------
static __device__ __forceinline__ int sigma_k(int t) {
    return (t & 32) | ((t & 4) << 2) | ((t & 24) >> 1) | (t & 3);
}

__global__ __launch_bounds__(256) void mfma_attn_kernel(
    const bf16* __restrict__ Kb, const bf16* __restrict__ Vt, bf16* __restrict__ QC)
{
    __shared__ bf16 Ks[2][64][72];
    __shared__ bf16 Vts[2][64][72];

    int l = blockIdx.x;
    l = (l & 7) * 256 + (l >> 3);      // XCD chunk swizzle
    const int qb = l & 3;
    const int h = (l >> 2) & 15;
    const int b = l >> 6;
    const int tid = threadIdx.x;
    const int lane = tid & 63;
    const int w = tid >> 6;
    const int lr = lane & 15, lg = lane >> 4;

    const int qrow0 = qb * 128 + w * 32;
    const size_t qbase = ((size_t)b * T_ + qrow0) * NQ_ + h * 64;
    const int bh = b * HN_ + h;

    bf16x8 qf[2][2];
#pragma unroll
    for (int mi = 0; mi < 2; mi++)
#pragma unroll
        for (int kc = 0; kc < 2; kc++)
            qf[mi][kc] = *(const bf16x8*)(QC + qbase + (size_t)(mi * 16 + lr) * NQ_ + kc * 32 + lg * 8);

    const f32x4 zero4 = {0.f, 0.f, 0.f, 0.f};
    f32x4 o[2][4];
    float m_st[2] = {-1e30f, -1e30f}, l_st[2] = {0.f, 0.f};
#pragma unroll
    for (int mi = 0; mi < 2; mi++)
#pragma unroll
        for (int dj = 0; dj < 4; dj++) o[mi][dj] = zero4;

    const int nsb = 2 * qb + 2;

    bf16x8 kreg[2], vreg[2];
    auto LOADR = [&](int sb) {
#pragma unroll
        for (int i = 0; i < 2; i++) {
            const int ci = i * 256 + tid, row = ci >> 3, cc = ci & 7;
            kreg[i] = *(const bf16x8*)(Kb + ((size_t)b * T_ + sb * 64 + row) * NQ_ + h * 64 + cc * 8);
            vreg[i] = *(const bf16x8*)(Vt + ((size_t)bh * 64 + row) * T_ + sb * 64 + cc * 8);
        }
    };
    auto WRITE = [&](int buf) {
#pragma unroll
        for (int i = 0; i < 2; i++) {
            const int ci = i * 256 + tid, row = ci >> 3, cc = ci & 7;
            *(bf16x8*)&Ks[buf][sigma_k(row)][cc * 8] = kreg[i];
            *(bf16x8*)&Vts[buf][row][cc * 8] = vreg[i];
        }
    };

    LOADR(0); WRITE(0); __syncthreads();
    int cur = 0;

    for (int sb = 0; sb < nsb; sb++) {
        const bool pf = (sb + 1 < nsb);
        if (pf) LOADR(sb + 1);

        if (sb * 64 <= qrow0 + 31) {
            f32x4 sc[2][4];
#pragma unroll
            for (int mi = 0; mi < 2; mi++)
#pragma unroll
                for (int nj = 0; nj < 4; nj++) sc[mi][nj] = zero4;
            __builtin_amdgcn_s_setprio(1);
#pragma unroll
            for (int kc = 0; kc < 2; kc++) {
                bf16x8 kf[4];
#pragma unroll
                for (int nj = 0; nj < 4; nj++)
                    kf[nj] = *(const bf16x8*)&Ks[cur][nj * 16 + lr][kc * 32 + lg * 8];
#pragma unroll
                for (int mi = 0; mi < 2; mi++)
#pragma unroll
                    for (int nj = 0; nj < 4; nj++)
                        sc[mi][nj] = mfma16(kf[nj], qf[mi][kc], sc[mi][nj]);
            }
            __builtin_amdgcn_s_setprio(0);
            const bool needmask = (sb * 64 + 63 > qrow0);
            float tm[2];
#pragma unroll
            for (int mi = 0; mi < 2; mi++) {
                const int qg = qrow0 + mi * 16 + lr;
                float mx = -1e30f;
#pragma unroll
                for (int nj = 0; nj < 4; nj++) {
                    const int kvb = sb * 64 + ((nj >> 1) << 5) + ((nj & 1) << 2) + lg * 8;
#pragma unroll
                    for (int r = 0; r < 4; r++) {
                        float s = sc[mi][nj][r];
                        if (needmask && (kvb + r > qg)) s = -1e30f;
                        sc[mi][nj][r] = s;
                        mx = fmaxf(mx, s);
                    }
                }
                mx = fmaxf(mx, __shfl_xor(mx, 16));
                mx = fmaxf(mx, __shfl_xor(mx, 32));
                tm[mi] = mx;
            }
            const bool defer = (tm[0] <= m_st[0] + 8.f) && (tm[1] <= m_st[1] + 8.f);
            if (!__all(defer)) {
#pragma unroll
                for (int mi = 0; mi < 2; mi++) {
                    const float mn = fmaxf(m_st[mi], tm[mi]);
                    const float sf = __expf(m_st[mi] - mn);
                    m_st[mi] = mn;
                    l_st[mi] *= sf;
#pragma unroll
                    for (int dj = 0; dj < 4; dj++)
#pragma unroll
                        for (int r = 0; r < 4; r++) o[mi][dj][r] *= sf;
                }
            }
            bf16x4 pk[2][4];
#pragma unroll
            for (int mi = 0; mi < 2; mi++) {
                float ts = 0.f;
#pragma unroll
                for (int nj = 0; nj < 4; nj++)
#pragma unroll
                    for (int r = 0; r < 4; r++) {
                        const float p2 = __expf(sc[mi][nj][r] - m_st[mi]);
                        ts += p2;
                        pk[mi][nj][r] = (bf16)p2;
                    }
                ts += __shfl_xor(ts, 16);
                ts += __shfl_xor(ts, 32);
                l_st[mi] += ts;
            }
            __builtin_amdgcn_s_setprio(1);
#pragma unroll
            for (int kc = 0; kc < 2; kc++) {
                bf16x8 vf[4], pf2[2];
#pragma unroll
                for (int mi = 0; mi < 2; mi++) {
                    bf16x8 t;
#pragma unroll
                    for (int r = 0; r < 4; r++) { t[r] = pk[mi][2 * kc][r]; t[r + 4] = pk[mi][2 * kc + 1][r]; }
                    pf2[mi] = t;
                }
#pragma unroll
                for (int dj = 0; dj < 4; dj++)
                    vf[dj] = *(const bf16x8*)&Vts[cur][dj * 16 + lr][kc * 32 + lg * 8];
#pragma unroll
                for (int mi = 0; mi < 2; mi++)
#pragma unroll
                    for (int dj = 0; dj < 4; dj++)
                        o[mi][dj] = mfma16(vf[dj], pf2[mi], o[mi][dj]);
            }
            __builtin_amdgcn_s_setprio(0);
        }

        if (pf) WRITE(cur ^ 1);
        __syncthreads();
        cur ^= 1;
    }

#pragma unroll
    for (int mi = 0; mi < 2; mi++) {
        const float inv = 1.f / l_st[mi];
        const size_t rowoff = qbase + (size_t)(mi * 16 + lr) * NQ_;
#pragma unroll
        for (int dj = 0; dj < 4; dj++) {
            bf16x4 st;
#pragma unroll
            for (int r = 0; r < 4; r++) st[r] = (bf16)(o[mi][dj][r] * inv);
            *(bf16x4*)(QC + rowoff + dj * 16 + lg * 4) = st;
        }
    }
}

// ---------------------------------------------------------------------------
extern "C" void kernel_launch(void* const* d_in, const int* in_sizes, int n_in,
                              void* d_out, int out_size, void* d_ws, size_t ws_size,
                              hipStream_t stream)
{
    const float* inputs = (const float*)d_in[0];
    const float* Wq = (const float*)d_in[1];
    const float* bq = (const float*)d_in[2];
    const float* Wk = (const float*)d_in[3];
    const float* bk = (const float*)d_in[4];
    const float* Wv = (const float*)d_in[5];
    const float* bv = (const float*)d_in[6];
    const float* Wr = (const float*)d_in[7];
    const float* br = (const float*)d_in[8];
    const float* Wo = (const float*)d_in[9];
    const float* bo = (const float*)d_in[10];
    const float* ln1w = (const float*)d_in[11];
    const float* ln1b = (const float*)d_in[12];
    const float* Wfc = (const float*)d_in[13];
    const float* bfc = (const float*)d_in[14];
    const float* ln2w = (const float*)d_in[15];
    const float* ln2b = (const float*)d_in[16];
    float* out = (float*)d_out;

    // Workspace layout (~117 MB):
    const size_t MB = 1024ull * 1024ull;
    char* ws = (char*)d_ws;
    bf16* qc   = (bf16*)(ws);               // 32MB [M][1024] q -> attn out (in place)
    bf16* kb   = (bf16*)(ws + 32 * MB);     // 32MB [M][1024] k
    bf16* vt   = (bf16*)(ws + 64 * MB);     // 32MB v^T
    bf16* xin  = (bf16*)(ws + 96 * MB);     // 16MB bf16 inputs
    bf16* wall = (bf16*)(ws + 112 * MB);    // 3.5MB [3584][512] Wq|Wk|Wv|Wr
    bf16* wot  = (bf16*)(ws + 112 * MB + 3670016);            // 1MB [512][1024]
    bf16* wfct = (bf16*)(ws + 112 * MB + 3670016 + 1048576);  // 0.5MB [512][512]
    float* ball = (float*)(ws + 112 * MB + 3670016 + 1048576 + 524288);  // 14KB
    float* resf = out;                      // residual f32, final row positions

    const dim3 blk(256);

    // fused prep (conv | headw | plain | bias)
    prep_all_kernel<<<dim3(4750), blk, 0, stream>>>(
        inputs, Wq, Wk, Wv, Wr, Wo, Wfc, bq, bk, bv, br,
        xin, wall, wall + (size_t)3072 * 512, wot, wfct, ball);

    // fused QKV + residual projection (N=3584), r9 fine 4-phase pipeline
    gemm_qkvr256_kernel<<<dim3(14, 64), dim3(512), 0, stream>>>(
        xin, wall, ball, qc, kb, vt, resf);
    // attention (in place over qc), KVBLK=64 (r11 best)
    mfma_attn_kernel<<<dim3(B_ * HN_ * 4), blk, 0, stream>>>(kb, vt, qc);
    // fused tail: Wo-GEMM + LN1 (LDS-resident) + fc-GEMM + LN2 -> f32 out
    gemm_ln_fused_kernel<<<dim3(256), dim3(512), 0, stream>>>(
        qc, wot, bo, resf, ln1w, ln1b, wfct, bfc, ln2w, ln2b, out);
}

// Round 15
// 233.292 us; speedup vs baseline: 1.0367x; 1.0367x over previous
//
#include <hip/hip_runtime.h>
#include <hip/hip_bf16.h>

// Problem constants
#define B_  32
#define T_  512
#define D_  512
#define HD_ 64
#define HN_ 16
#define O_  512
#define M_  (B_ * T_)      // 16384 rows
#define NQ_ (HN_ * HD_)    // 1024 qkv cols

typedef __bf16 bf16;
typedef __attribute__((ext_vector_type(8))) __bf16 bf16x8;
typedef __attribute__((ext_vector_type(4))) __bf16 bf16x4;
typedef __attribute__((ext_vector_type(4))) float f32x4;

static __device__ __forceinline__ f32x4 mfma16(bf16x8 a, bf16x8 b, f32x4 c) {
    return __builtin_amdgcn_mfma_f32_16x16x32_bf16(a, b, c, 0, 0, 0);
}

// Direct global->LDS 16B copy.
static __device__ __forceinline__ void load_lds_16B(const bf16* g, bf16* l) {
    __builtin_amdgcn_global_load_lds(
        (const __attribute__((address_space(1))) unsigned int*)(unsigned long long)g,
        (__attribute__((address_space(3))) unsigned int*)(unsigned long long)l,
        16, 0, 0);
}

static __device__ __forceinline__ float fast_tanh(float x) {
    return 1.f - 2.f / (__expf(2.f * x) + 1.f);
}

// T1 chunked XCD swizzle: requires (gridDim.x*gridDim.y) % 8 == 0.
static __device__ __forceinline__ int2 swz_block() {
    const int nx = gridDim.x;
    const int nwg = nx * gridDim.y;
    int l = blockIdx.y * nx + blockIdx.x;
    l = (l & 7) * (nwg >> 3) + (l >> 3);
    return make_int2(l % nx, l / nx);
}

// ---------------------------------------------------------------------------
// Fused prep: conv_input (4096 blocks) | headw (384) | plain (256) | bias (14).
// ---------------------------------------------------------------------------
__global__ __launch_bounds__(256) void prep_all_kernel(
    const float* __restrict__ inputs,
    const float* __restrict__ Wq, const float* __restrict__ Wk,
    const float* __restrict__ Wv, const float* __restrict__ Wr,
    const float* __restrict__ Wo, const float* __restrict__ Wfc,
    const float* __restrict__ bq, const float* __restrict__ bk,
    const float* __restrict__ bv, const float* __restrict__ br,
    bf16* __restrict__ xin, bf16* __restrict__ wall,
    bf16* __restrict__ wrt, bf16* __restrict__ wot, bf16* __restrict__ wfct,
    float* __restrict__ ball)
{
    __shared__ bf16 tl[64][72];
    const int tid = threadIdx.x;
    int id = blockIdx.x;

    if (id < 4096) {
        const size_t i = ((size_t)id * 256 + tid) * 8;
        f32x4 x0 = *(const f32x4*)(inputs + i);
        f32x4 x1 = *(const f32x4*)(inputs + i + 4);
        bf16x8 v;
        v[0] = (bf16)x0[0]; v[1] = (bf16)x0[1]; v[2] = (bf16)x0[2]; v[3] = (bf16)x0[3];
        v[4] = (bf16)x1[0]; v[5] = (bf16)x1[1]; v[6] = (bf16)x1[2]; v[7] = (bf16)x1[3];
        *(bf16x8*)(xin + i) = v;
        return;
    }
    if (id < 4480) {
        id -= 4096;
        const int kt = id & 7; id >>= 3;
        const int h = id & 15; id >>= 4;
        const float* src = (id == 0) ? Wq : (id == 1) ? Wk : Wv;
        bf16* dst = wall + (size_t)id * (1024 * 512);
        const int k0 = kt * 64;
#pragma unroll
        for (int i = 0; i < 4; i++) {
            const int e = i * 256 + tid;
            const int kk = e >> 4, f4 = (e & 15) * 4;
            const f32x4 v = *(const f32x4*)(src + ((size_t)h * 512 + k0 + kk) * 64 + f4);
#pragma unroll
            for (int j = 0; j < 4; j++) tl[f4 + j][kk] = (bf16)v[j];
        }
        __syncthreads();
#pragma unroll
        for (int i = 0; i < 2; i++) {
            const int e = i * 256 + tid;
            const int f = e >> 3, kc = (e & 7) * 8;
            *(bf16x8*)(dst + ((size_t)h * 64 + f) * 512 + k0 + kc) = *(const bf16x8*)&tl[f][kc];
        }
        return;
    }
    if (id < 4736) {
        id -= 4480;
        const float* src; bf16* dst; int K;
        if (id < 64)       { src = Wr;  dst = wrt;  K = 512;  }
        else if (id < 192) { src = Wo;  dst = wot;  K = 1024; id -= 64; }
        else               { src = Wfc; dst = wfct; K = 512;  id -= 192; }
        const int kt = id >> 3, nt = id & 7;
        const int k0 = kt * 64, n0 = nt * 64;
#pragma unroll
        for (int i = 0; i < 4; i++) {
            const int e = i * 256 + tid;
            const int kk = e >> 4, n4 = (e & 15) * 4;
            const f32x4 v = *(const f32x4*)(src + (size_t)(k0 + kk) * 512 + n0 + n4);
#pragma unroll
            for (int j = 0; j < 4; j++) tl[n4 + j][kk] = (bf16)v[j];
        }
        __syncthreads();
#pragma unroll
        for (int i = 0; i < 2; i++) {
            const int e = i * 256 + tid;
            const int nn = e >> 3, kc = (e & 7) * 8;
            *(bf16x8*)(dst + (size_t)(n0 + nn) * K + k0 + kc) = *(const bf16x8*)&tl[nn][kc];
        }
        return;
    }
    const int i = (id - 4736) * 256 + tid;  // 0..3583
    float v = (i < 1024) ? bq[i]
            : (i < 2048) ? bk[i - 1024]
            : (i < 3072) ? bv[i - 2048] : br[i - 3072];
    ball[i] = v;
}

// ---------------------------------------------------------------------------
// QKV+R GEMM, 256x256, BK=64, 8 waves, fine 4-phase counted-vmcnt
// (r9 schedule + r14 f32 residual direct store — measured 88.4 us, frozen).
// ---------------------------------------------------------------------------
__global__ __launch_bounds__(512, 2) void gemm_qkvr256_kernel(
    const bf16* __restrict__ A, const bf16* __restrict__ Wall,
    const float* __restrict__ ball,
    bf16* __restrict__ qc, bf16* __restrict__ kb, bf16* __restrict__ vt,
    float* __restrict__ resf)
{
    __shared__ bf16 SL[65536];   // 128 KB
    const int tid = threadIdx.x;
    const int lane = tid & 63;
    const int w = tid >> 6;
    const int wm = w >> 2, wn = w & 3;
    const int lr = lane & 15, lg = lane >> 4;
    const int K = 512;

    const int2 bc = swz_block();
    const int m0 = bc.y * 256, n0 = bc.x * 256;

    const int p = tid & 7;
    const int rr = tid >> 3;
    const int g = p ^ (rr & 7);
    const int arow0 = rr, arow1 = 128 + rr;
    const int brow0 = ((rr >> 5) << 6) | (rr & 31);
    const int brow1 = 128 + brow0;

    auto STAGE_H = [&](int t, int h) {
        const int slot = t & 1;
        const int k0 = t << 6;
        if ((h & 1) == 0) {
            bf16* Bb = SL + 32768 + slot * 16384;
            const int off = (h == 2) ? 32 : 0;
            const int r0_ = brow0 + off, r1_ = brow1 + off;
            load_lds_16B(Wall + (size_t)(n0 + r0_) * K + k0 + g * 8, Bb + r0_ * 64 + p * 8);
            load_lds_16B(Wall + (size_t)(n0 + r1_) * K + k0 + g * 8, Bb + r1_ * 64 + p * 8);
        } else {
            bf16* Ab = SL + slot * 16384;
            const int off = (h == 3) ? 64 : 0;
            const int r0_ = arow0 + off, r1_ = arow1 + off;
            load_lds_16B(A + (size_t)(m0 + r0_) * K + k0 + g * 8, Ab + r0_ * 64 + p * 8);
            load_lds_16B(A + (size_t)(m0 + r1_) * K + k0 + g * 8, Ab + r1_ * 64 + p * 8);
        }
    };

    const int x = lr & 7;
    auto LDA = [&](int t, int mi, int kc) -> bf16x8 {
        const int row = wm * 128 + mi * 16 + lr;
        const bf16* Ab = SL + (t & 1) * 16384;
        return *(const bf16x8*)&Ab[row * 64 + ((((kc << 2) | lg) ^ x) << 3)];
    };
    auto LDB = [&](int t, int nj, int kc) -> bf16x8 {
        const int row = wn * 64 + nj * 16 + lr;
        const bf16* Bb = SL + 32768 + (t & 1) * 16384;
        return *(const bf16x8*)&Bb[row * 64 + ((((kc << 2) | lg) ^ x) << 3)];
    };

    f32x4 acc[8][4];
    const f32x4 zero4 = {0.f, 0.f, 0.f, 0.f};
#pragma unroll
    for (int i = 0; i < 8; i++)
#pragma unroll
        for (int j = 0; j < 4; j++) acc[i][j] = zero4;

    bf16x8 b01[4], b23[4], af[8];

    STAGE_H(0, 0); STAGE_H(0, 1); STAGE_H(0, 2); STAGE_H(0, 3);

    for (int t = 0; t < 7; t++) {
        asm volatile("s_waitcnt vmcnt(4)\n\ts_barrier" ::: "memory");
#pragma unroll
        for (int nj = 0; nj < 2; nj++)
#pragma unroll
            for (int kc = 0; kc < 2; kc++) b01[nj * 2 + kc] = LDB(t, nj, kc);
#pragma unroll
        for (int mi = 0; mi < 4; mi++)
#pragma unroll
            for (int kc = 0; kc < 2; kc++) af[mi * 2 + kc] = LDA(t, mi, kc);
        STAGE_H(t + 1, 0);
        __builtin_amdgcn_s_setprio(1);
#pragma unroll
        for (int mi = 0; mi < 4; mi++)
#pragma unroll
            for (int nj = 0; nj < 2; nj++)
#pragma unroll
                for (int kc = 0; kc < 2; kc++)
                    acc[mi][nj] = mfma16(af[mi * 2 + kc], b01[nj * 2 + kc], acc[mi][nj]);
        __builtin_amdgcn_s_setprio(0);
        asm volatile("s_waitcnt vmcnt(4)\n\ts_barrier" ::: "memory");
#pragma unroll
        for (int nj = 0; nj < 2; nj++)
#pragma unroll
            for (int kc = 0; kc < 2; kc++) b23[nj * 2 + kc] = LDB(t, nj + 2, kc);
        STAGE_H(t + 1, 1);
        __builtin_amdgcn_s_setprio(1);
#pragma unroll
        for (int mi = 0; mi < 4; mi++)
#pragma unroll
            for (int nj = 0; nj < 2; nj++)
#pragma unroll
                for (int kc = 0; kc < 2; kc++)
                    acc[mi][nj + 2] = mfma16(af[mi * 2 + kc], b23[nj * 2 + kc], acc[mi][nj + 2]);
        __builtin_amdgcn_s_setprio(0);
        asm volatile("s_waitcnt vmcnt(4)\n\ts_barrier" ::: "memory");
#pragma unroll
        for (int mi = 0; mi < 4; mi++)
#pragma unroll
            for (int kc = 0; kc < 2; kc++) af[mi * 2 + kc] = LDA(t, mi + 4, kc);
        STAGE_H(t + 1, 2);
        __builtin_amdgcn_s_setprio(1);
#pragma unroll
        for (int mi = 0; mi < 4; mi++)
#pragma unroll
            for (int nj = 0; nj < 2; nj++)
#pragma unroll
                for (int kc = 0; kc < 2; kc++)
                    acc[mi + 4][nj] = mfma16(af[mi * 2 + kc], b01[nj * 2 + kc], acc[mi + 4][nj]);
        __builtin_amdgcn_s_setprio(0);
        STAGE_H(t + 1, 3);
        __builtin_amdgcn_s_setprio(1);
#pragma unroll
        for (int mi = 0; mi < 4; mi++)
#pragma unroll
            for (int nj = 0; nj < 2; nj++)
#pragma unroll
                for (int kc = 0; kc < 2; kc++)
                    acc[mi + 4][nj + 2] = mfma16(af[mi * 2 + kc], b23[nj * 2 + kc], acc[mi + 4][nj + 2]);
        __builtin_amdgcn_s_setprio(0);
    }

    {
        const int t = 7;
        asm volatile("s_waitcnt vmcnt(4)\n\ts_barrier" ::: "memory");
#pragma unroll
        for (int nj = 0; nj < 2; nj++)
#pragma unroll
            for (int kc = 0; kc < 2; kc++) b01[nj * 2 + kc] = LDB(t, nj, kc);
#pragma unroll
        for (int mi = 0; mi < 4; mi++)
#pragma unroll
            for (int kc = 0; kc < 2; kc++) af[mi * 2 + kc] = LDA(t, mi, kc);
        __builtin_amdgcn_s_setprio(1);
#pragma unroll
        for (int mi = 0; mi < 4; mi++)
#pragma unroll
            for (int nj = 0; nj < 2; nj++)
#pragma unroll
                for (int kc = 0; kc < 2; kc++)
                    acc[mi][nj] = mfma16(af[mi * 2 + kc], b01[nj * 2 + kc], acc[mi][nj]);
        __builtin_amdgcn_s_setprio(0);
        asm volatile("s_waitcnt vmcnt(2)\n\ts_barrier" ::: "memory");
#pragma unroll
        for (int nj = 0; nj < 2; nj++)
#pragma unroll
            for (int kc = 0; kc < 2; kc++) b23[nj * 2 + kc] = LDB(t, nj + 2, kc);
        __builtin_amdgcn_s_setprio(1);
#pragma unroll
        for (int mi = 0; mi < 4; mi++)
#pragma unroll
            for (int nj = 0; nj < 2; nj++)
#pragma unroll
                for (int kc = 0; kc < 2; kc++)
                    acc[mi][nj + 2] = mfma16(af[mi * 2 + kc], b23[nj * 2 + kc], acc[mi][nj + 2]);
        __builtin_amdgcn_s_setprio(0);
        asm volatile("s_waitcnt vmcnt(0)\n\ts_barrier" ::: "memory");
#pragma unroll
        for (int mi = 0; mi < 4; mi++)
#pragma unroll
            for (int kc = 0; kc < 2; kc++) af[mi * 2 + kc] = LDA(t, mi + 4, kc);
        __builtin_amdgcn_s_setprio(1);
#pragma unroll
        for (int mi = 0; mi < 4; mi++)
#pragma unroll
            for (int nj = 0; nj < 2; nj++)
#pragma unroll
                for (int kc = 0; kc < 2; kc++)
                    acc[mi + 4][nj] = mfma16(af[mi * 2 + kc], b01[nj * 2 + kc], acc[mi + 4][nj]);
#pragma unroll
        for (int mi = 0; mi < 4; mi++)
#pragma unroll
            for (int nj = 0; nj < 2; nj++)
#pragma unroll
                for (int kc = 0; kc < 2; kc++)
                    acc[mi + 4][nj + 2] = mfma16(af[mi * 2 + kc], b23[nj * 2 + kc], acc[mi + 4][nj + 2]);
        __builtin_amdgcn_s_setprio(0);
    }
    __syncthreads();

    const int region = n0 >> 10;
    if (region == 2) {
#pragma unroll
        for (int mi = 0; mi < 8; mi++) {
#pragma unroll
            for (int nj = 0; nj < 4; nj++) {
                const int n = n0 + wn * 64 + nj * 16 + lr;
                const float bn = ball[n];
                const int m = m0 + wm * 128 + mi * 16 + lg * 4;
                const int bb = m >> 9, tt = m & 511;
                const int nn = n - 2048, hh = nn >> 6, f = nn & 63;
                bf16x4 st;
#pragma unroll
                for (int r = 0; r < 4; r++) st[r] = (bf16)fast_tanh(acc[mi][nj][r] + bn);
                *(bf16x4*)(vt + (((size_t)(bb * 16 + hh) * 64 + f) << 9) + tt) = st;
            }
        }
    } else if (region == 3) {
        // residual: f32 direct store into d_out at final row positions
#pragma unroll
        for (int mi = 0; mi < 8; mi++) {
#pragma unroll
            for (int nj = 0; nj < 4; nj++) {
                const int n = n0 + wn * 64 + nj * 16 + lr;
                const float bn = ball[n];
                const int nn = n - 3072;
#pragma unroll
                for (int r = 0; r < 4; r++) {
                    const int m = m0 + wm * 128 + mi * 16 + lg * 4 + r;
                    resf[(size_t)m * 512 + nn] = acc[mi][nj][r] + bn;
                }
            }
        }
    } else {
        bf16* dst; int nb; float scale = 1.f;
        if (region == 0) { dst = qc; nb = n0;        scale = 0.125f; }
        else             { dst = kb; nb = n0 - 1024; }
        float bn[4];
#pragma unroll
        for (int nj = 0; nj < 4; nj++) bn[nj] = ball[n0 + wn * 64 + nj * 16 + lr];
#pragma unroll
        for (int half = 0; half < 2; half++) {
            if (wm == half) {
#pragma unroll
                for (int mi = 0; mi < 8; mi++) {
#pragma unroll
                    for (int nj = 0; nj < 4; nj++) {
                        const int col = wn * 64 + nj * 16 + lr;
#pragma unroll
                        for (int r = 0; r < 4; r++) {
                            float v = fmaxf(acc[mi][nj][r] + bn[nj], 0.f);
                            SL[(mi * 16 + lg * 4 + r) * 264 + col] = (bf16)(v * scale);
                        }
                    }
                }
            }
            __syncthreads();
#pragma unroll
            for (int i = 0; i < 4; i++) {
                const int rr2 = i * 32 + (tid >> 4);
                const int cc = (tid & 15) * 16;
                bf16x8 v0 = *(const bf16x8*)&SL[rr2 * 264 + cc];
                bf16x8 v1 = *(const bf16x8*)&SL[rr2 * 264 + cc + 8];
                bf16* pdst = dst + (size_t)(m0 + half * 128 + rr2) * 1024 + nb + cc;
                *(bf16x8*)pdst = v0;
                *(bf16x8*)(pdst + 8) = v1;
            }
            __syncthreads();
        }
    }
}

// ---------------------------------------------------------------------------
// GEMM + fused LayerNorm, 8-wave (r11 measured-best split-tail version).
// PF32: partner tensor is f32 (residual in d_out), else bf16.
// ---------------------------------------------------------------------------
template <int ACT, bool F32OUT, bool PF32>
__global__ __launch_bounds__(512) void gemm_ln_kernel(
    const bf16* __restrict__ A, const bf16* __restrict__ Wt,
    const float* __restrict__ bias, const void* __restrict__ partner,
    const float* __restrict__ lnw, const float* __restrict__ lnb,
    void* __restrict__ outv, const int K)
{
    __shared__ bf16 SL[73728];          // A slots 4x2048 @0; B slots 4x16384 @8192
    __shared__ float parts[2][4][64];
    const int tid = threadIdx.x;
    const int lane = tid & 63;
    const int w = tid >> 6;
    const int wr = w >> 2, wn = w & 3;
    const int lr = lane & 15, lg = lane >> 4;
    const int m0 = blockIdx.x * 64;
    const int nt = K >> 5;

    const int gs = (tid & 3) ^ ((tid >> 3) & 3);
    const bf16* aP = A + (size_t)(m0 + (tid >> 2)) * K + gs * 8;
    const bf16* bP = Wt + (size_t)(tid >> 2) * K + gs * 8;

    auto STAGE = [&](int t) {
        bf16* Ab = SL + (t & 3) * 2048;
        bf16* Bb = SL + 8192 + (t & 3) * 16384;
        const int k0 = t << 5;
        if (tid < 256) load_lds_16B(aP + k0, Ab + tid * 8);
#pragma unroll
        for (int j = 0; j < 4; j++)
            load_lds_16B(bP + k0 + (size_t)(j * 128) * K, Bb + j * 4096 + tid * 8);
    };

    f32x4 acc[2][8];
    const f32x4 zero4 = {0.f, 0.f, 0.f, 0.f};
#pragma unroll
    for (int i = 0; i < 2; i++)
#pragma unroll
        for (int j = 0; j < 8; j++) acc[i][j] = zero4;

    STAGE(0); STAGE(1);
    if (w < 4) asm volatile("s_waitcnt vmcnt(5)" ::: "memory");
    else       asm volatile("s_waitcnt vmcnt(4)" ::: "memory");
    __builtin_amdgcn_s_barrier();

    for (int t = 0; t < nt; t++) {
        if (t + 2 < nt) {
            STAGE(t + 2);
            if (w < 4) asm volatile("s_waitcnt vmcnt(5)" ::: "memory");
            else       asm volatile("s_waitcnt vmcnt(4)" ::: "memory");
        } else {
            asm volatile("s_waitcnt vmcnt(0)" ::: "memory");
        }
        __builtin_amdgcn_s_barrier();

        const bf16* Ab = SL + (t & 3) * 2048;
        const bf16* Bb = SL + 8192 + (t & 3) * 16384;
        bf16x8 a[2], b[8];
#pragma unroll
        for (int mi = 0; mi < 2; mi++) {
            const int row = wr * 32 + mi * 16 + lr;
            a[mi] = *(const bf16x8*)&Ab[row * 32 + ((lg ^ ((row >> 1) & 3)) << 3)];
        }
#pragma unroll
        for (int nj = 0; nj < 8; nj++) {
            const int row = wn * 128 + nj * 16 + lr;
            b[nj] = *(const bf16x8*)&Bb[row * 32 + ((lg ^ ((row >> 1) & 3)) << 3)];
        }
        __builtin_amdgcn_s_setprio(1);
#pragma unroll
        for (int mi = 0; mi < 2; mi++)
#pragma unroll
            for (int nj = 0; nj < 8; nj++)
                acc[mi][nj] = mfma16(a[mi], b[nj], acc[mi][nj]);
        __builtin_amdgcn_s_setprio(0);
    }
    __syncthreads();

    // stage partner tile -> SLp bf16 [64][520]
    bf16* SLp = SL;
#pragma unroll
    for (int jj = 0; jj < 8; jj++) {
        const int e = jj * 512 + tid;
        const int row = e >> 6, col = (e & 63) * 8;
        if constexpr (PF32) {
            const float* pp = (const float*)partner + (size_t)(m0 + row) * 512 + col;
            const f32x4 u0 = *(const f32x4*)pp;
            const f32x4 u1 = *(const f32x4*)(pp + 4);
            bf16x8 v;
#pragma unroll
            for (int q = 0; q < 4; q++) { v[q] = (bf16)u0[q]; v[4 + q] = (bf16)u1[q]; }
            *(bf16x8*)&SLp[row * 520 + col] = v;
        } else {
            *(bf16x8*)&SLp[row * 520 + col] =
                *(const bf16x8*)((const bf16*)partner + (size_t)(m0 + row) * 512 + col);
        }
    }
    __syncthreads();

    float bn[8], lw[8], lb[8];
#pragma unroll
    for (int nj = 0; nj < 8; nj++) {
        const int col = wn * 128 + nj * 16 + lr;
        bn[nj] = bias[col]; lw[nj] = lnw[col]; lb[nj] = lnb[col];
    }

    float rs[8], rq[8];
#pragma unroll
    for (int mi = 0; mi < 2; mi++)
#pragma unroll
        for (int r = 0; r < 4; r++) {
            const int row = wr * 32 + mi * 16 + lg * 4 + r;
            float ps = 0.f, pq = 0.f;
#pragma unroll
            for (int nj = 0; nj < 8; nj++) {
                float xv = acc[mi][nj][r] + bn[nj];
                if constexpr (ACT == 1) xv = fmaxf(xv, 0.f);
                else if constexpr (ACT == 2) xv = fast_tanh(xv);
                xv += (float)SLp[row * 520 + wn * 128 + nj * 16 + lr];
                acc[mi][nj][r] = xv;
                ps += xv; pq += xv * xv;
            }
            rs[mi * 4 + r] = ps; rq[mi * 4 + r] = pq;
        }
#pragma unroll
    for (int i = 0; i < 8; i++) {
#pragma unroll
        for (int off = 1; off <= 8; off <<= 1) {
            rs[i] += __shfl_xor(rs[i], off);
            rq[i] += __shfl_xor(rq[i], off);
        }
    }
    if (lr == 0) {
#pragma unroll
        for (int mi = 0; mi < 2; mi++)
#pragma unroll
            for (int r = 0; r < 4; r++) {
                const int row = wr * 32 + mi * 16 + lg * 4 + r;
                parts[0][wn][row] = rs[mi * 4 + r];
                parts[1][wn][row] = rq[mi * 4 + r];
            }
    }
    __syncthreads();

    float mean_[8], inv_[8];
#pragma unroll
    for (int mi = 0; mi < 2; mi++)
#pragma unroll
        for (int r = 0; r < 4; r++) {
            const int row = wr * 32 + mi * 16 + lg * 4 + r;
            const float S = parts[0][0][row] + parts[0][1][row] + parts[0][2][row] + parts[0][3][row];
            const float Q = parts[1][0][row] + parts[1][1][row] + parts[1][2][row] + parts[1][3][row];
            const float m = S * (1.f / 512.f);
            mean_[mi * 4 + r] = m;
            inv_[mi * 4 + r] = rsqrtf(Q * (1.f / 512.f) - m * m + 1e-5f);
        }

    if constexpr (F32OUT) {
        float* outp = (float*)outv;
#pragma unroll
        for (int mi = 0; mi < 2; mi++)
#pragma unroll
            for (int r = 0; r < 4; r++) {
                const int row = wr * 32 + mi * 16 + lg * 4 + r;
                const float m = mean_[mi * 4 + r], iv = inv_[mi * 4 + r];
#pragma unroll
                for (int nj = 0; nj < 8; nj++) {
                    const int col = wn * 128 + nj * 16 + lr;
                    outp[(size_t)(m0 + row) * 512 + col] =
                        (acc[mi][nj][r] - m) * iv * lw[nj] + lb[nj];
                }
            }
    } else {
        bf16* SLy = SL + 36864;
#pragma unroll
        for (int mi = 0; mi < 2; mi++)
#pragma unroll
            for (int r = 0; r < 4; r++) {
                const int row = wr * 32 + mi * 16 + lg * 4 + r;
                const float m = mean_[mi * 4 + r], iv = inv_[mi * 4 + r];
#pragma unroll
                for (int nj = 0; nj < 8; nj++) {
                    const int col = wn * 128 + nj * 16 + lr;
                    SLy[row * 520 + col] = (bf16)((acc[mi][nj][r] - m) * iv * lw[nj] + lb[nj]);
                }
            }
        __syncthreads();
        bf16* outp = (bf16*)outv;
#pragma unroll
        for (int jj = 0; jj < 8; jj++) {
            const int e = jj * 512 + tid;
            const int row = e >> 6, col = (e & 63) * 8;
            *(bf16x8*)(outp + (size_t)(m0 + row) * 512 + col) =
                *(const bf16x8*)&SLy[row * 520 + col];
        }
    }
}

// ---------------------------------------------------------------------------
// MFMA flash attention (r11 measured-best version, KVBLK=64).
// ---------------------------------------------------------------------------
static __device__ __forceinline__ int sigma_k(int t) {
    return (t & 32) | ((t & 4) << 2) | ((t & 24) >> 1) | (t & 3);
}

__global__ __launch_bounds__(256) void mfma_attn_kernel(
    const bf16* __restrict__ Kb, const bf16* __restrict__ Vt, bf16* __restrict__ QC)
{
    __shared__ bf16 Ks[2][64][72];
    __shared__ bf16 Vts[2][64][72];

    int l = blockIdx.x;
    l = (l & 7) * 256 + (l >> 3);      // XCD chunk swizzle
    const int qb = l & 3;
    const int h = (l >> 2) & 15;
    const int b = l >> 6;
    const int tid = threadIdx.x;
    const int lane = tid & 63;
    const int w = tid >> 6;
    const int lr = lane & 15, lg = lane >> 4;

    const int qrow0 = qb * 128 + w * 32;
    const size_t qbase = ((size_t)b * T_ + qrow0) * NQ_ + h * 64;
    const int bh = b * HN_ + h;

    bf16x8 qf[2][2];
#pragma unroll
    for (int mi = 0; mi < 2; mi++)
#pragma unroll
        for (int kc = 0; kc < 2; kc++)
            qf[mi][kc] = *(const bf16x8*)(QC + qbase + (size_t)(mi * 16 + lr) * NQ_ + kc * 32 + lg * 8);

    const f32x4 zero4 = {0.f, 0.f, 0.f, 0.f};
    f32x4 o[2][4];
    float m_st[2] = {-1e30f, -1e30f}, l_st[2] = {0.f, 0.f};
#pragma unroll
    for (int mi = 0; mi < 2; mi++)
#pragma unroll
        for (int dj = 0; dj < 4; dj++) o[mi][dj] = zero4;

    const int nsb = 2 * qb + 2;

    bf16x8 kreg[2], vreg[2];
    auto LOADR = [&](int sb) {
#pragma unroll
        for (int i = 0; i < 2; i++) {
            const int ci = i * 256 + tid, row = ci >> 3, cc = ci & 7;
            kreg[i] = *(const bf16x8*)(Kb + ((size_t)b * T_ + sb * 64 + row) * NQ_ + h * 64 + cc * 8);
            vreg[i] = *(const bf16x8*)(Vt + ((size_t)bh * 64 + row) * T_ + sb * 64 + cc * 8);
        }
    };
    auto WRITE = [&](int buf) {
#pragma unroll
        for (int i = 0; i < 2; i++) {
            const int ci = i * 256 + tid, row = ci >> 3, cc = ci & 7;
            *(bf16x8*)&Ks[buf][sigma_k(row)][cc * 8] = kreg[i];
            *(bf16x8*)&Vts[buf][row][cc * 8] = vreg[i];
        }
    };

    LOADR(0); WRITE(0); __syncthreads();
    int cur = 0;

    for (int sb = 0; sb < nsb; sb++) {
        const bool pf = (sb + 1 < nsb);
        if (pf) LOADR(sb + 1);

        if (sb * 64 <= qrow0 + 31) {
            f32x4 sc[2][4];
#pragma unroll
            for (int mi = 0; mi < 2; mi++)
#pragma unroll
                for (int nj = 0; nj < 4; nj++) sc[mi][nj] = zero4;
            __builtin_amdgcn_s_setprio(1);
#pragma unroll
            for (int kc = 0; kc < 2; kc++) {
                bf16x8 kf[4];
#pragma unroll
                for (int nj = 0; nj < 4; nj++)
                    kf[nj] = *(const bf16x8*)&Ks[cur][nj * 16 + lr][kc * 32 + lg * 8];
#pragma unroll
                for (int mi = 0; mi < 2; mi++)
#pragma unroll
                    for (int nj = 0; nj < 4; nj++)
                        sc[mi][nj] = mfma16(kf[nj], qf[mi][kc], sc[mi][nj]);
            }
            __builtin_amdgcn_s_setprio(0);
            const bool needmask = (sb * 64 + 63 > qrow0);
            float tm[2];
#pragma unroll
            for (int mi = 0; mi < 2; mi++) {
                const int qg = qrow0 + mi * 16 + lr;
                float mx = -1e30f;
#pragma unroll
                for (int nj = 0; nj < 4; nj++) {
                    const int kvb = sb * 64 + ((nj >> 1) << 5) + ((nj & 1) << 2) + lg * 8;
#pragma unroll
                    for (int r = 0; r < 4; r++) {
                        float s = sc[mi][nj][r];
                        if (needmask && (kvb + r > qg)) s = -1e30f;
                        sc[mi][nj][r] = s;
                        mx = fmaxf(mx, s);
                    }
                }
                mx = fmaxf(mx, __shfl_xor(mx, 16));
                mx = fmaxf(mx, __shfl_xor(mx, 32));
                tm[mi] = mx;
            }
            const bool defer = (tm[0] <= m_st[0] + 8.f) && (tm[1] <= m_st[1] + 8.f);
            if (!__all(defer)) {
#pragma unroll
                for (int mi = 0; mi < 2; mi++) {
                    const float mn = fmaxf(m_st[mi], tm[mi]);
                    const float sf = __expf(m_st[mi] - mn);
                    m_st[mi] = mn;
                    l_st[mi] *= sf;
#pragma unroll
                    for (int dj = 0; dj < 4; dj++)
#pragma unroll
                        for (int r = 0; r < 4; r++) o[mi][dj][r] *= sf;
                }
            }
            bf16x4 pk[2][4];
#pragma unroll
            for (int mi = 0; mi < 2; mi++) {
                float ts = 0.f;
#pragma unroll
                for (int nj = 0; nj < 4; nj++)
#pragma unroll
                    for (int r = 0; r < 4; r++) {
                        const float p2 = __expf(sc[mi][nj][r] - m_st[mi]);
                        ts += p2;
                        pk[mi][nj][r] = (bf16)p2;
                    }
                ts += __shfl_xor(ts, 16);
                ts += __shfl_xor(ts, 32);
                l_st[mi] += ts;
            }
            __builtin_amdgcn_s_setprio(1);
#pragma unroll
            for (int kc = 0; kc < 2; kc++) {
                bf16x8 vf[4], pf2[2];
#pragma unroll
                for (int mi = 0; mi < 2; mi++) {
                    bf16x8 t;
#pragma unroll
                    for (int r = 0; r < 4; r++) { t[r] = pk[mi][2 * kc][r]; t[r + 4] = pk[mi][2 * kc + 1][r]; }
                    pf2[mi] = t;
                }
#pragma unroll
                for (int dj = 0; dj < 4; dj++)
                    vf[dj] = *(const bf16x8*)&Vts[cur][dj * 16 + lr][kc * 32 + lg * 8];
#pragma unroll
                for (int mi = 0; mi < 2; mi++)
#pragma unroll
                    for (int dj = 0; dj < 4; dj++)
                        o[mi][dj] = mfma16(vf[dj], pf2[mi], o[mi][dj]);
            }
            __builtin_amdgcn_s_setprio(0);
        }

        if (pf) WRITE(cur ^ 1);
        __syncthreads();
        cur ^= 1;
    }

#pragma unroll
    for (int mi = 0; mi < 2; mi++) {
        const float inv = 1.f / l_st[mi];
        const size_t rowoff = qbase + (size_t)(mi * 16 + lr) * NQ_;
#pragma unroll
        for (int dj = 0; dj < 4; dj++) {
            bf16x4 st;
#pragma unroll
            for (int r = 0; r < 4; r++) st[r] = (bf16)(o[mi][dj][r] * inv);
            *(bf16x4*)(QC + rowoff + dj * 16 + lg * 4) = st;
        }
    }
}

// ---------------------------------------------------------------------------
extern "C" void kernel_launch(void* const* d_in, const int* in_sizes, int n_in,
                              void* d_out, int out_size, void* d_ws, size_t ws_size,
                              hipStream_t stream)
{
    const float* inputs = (const float*)d_in[0];
    const float* Wq = (const float*)d_in[1];
    const float* bq = (const float*)d_in[2];
    const float* Wk = (const float*)d_in[3];
    const float* bk = (const float*)d_in[4];
    const float* Wv = (const float*)d_in[5];
    const float* bv = (const float*)d_in[6];
    const float* Wr = (const float*)d_in[7];
    const float* br = (const float*)d_in[8];
    const float* Wo = (const float*)d_in[9];
    const float* bo = (const float*)d_in[10];
    const float* ln1w = (const float*)d_in[11];
    const float* ln1b = (const float*)d_in[12];
    const float* Wfc = (const float*)d_in[13];
    const float* bfc = (const float*)d_in[14];
    const float* ln2w = (const float*)d_in[15];
    const float* ln2b = (const float*)d_in[16];
    float* out = (float*)d_out;

    // Workspace layout (~117 MB):
    const size_t MB = 1024ull * 1024ull;
    char* ws = (char*)d_ws;
    bf16* qc   = (bf16*)(ws);               // 32MB [M][1024] q -> attn out (in place)
    bf16* kb   = (bf16*)(ws + 32 * MB);     // 32MB [M][1024] k; ln1 in 2nd half post-attn
    bf16* vt   = (bf16*)(ws + 64 * MB);     // 32MB v^T
    bf16* xin  = (bf16*)(ws + 96 * MB);     // 16MB bf16 inputs
    bf16* wall = (bf16*)(ws + 112 * MB);    // 3.5MB [3584][512] Wq|Wk|Wv|Wr
    bf16* wot  = (bf16*)(ws + 112 * MB + 3670016);            // 1MB [512][1024]
    bf16* wfct = (bf16*)(ws + 112 * MB + 3670016 + 1048576);  // 0.5MB [512][512]
    float* ball = (float*)(ws + 112 * MB + 3670016 + 1048576 + 524288);  // 14KB
    float* resf = out;                      // residual f32 at final row positions
    bf16* ln1  = kb + (size_t)8 * MB;       // 16MB (second half of kb; kb dead post-attn)

    const dim3 blk(256);

    // fused prep (conv | headw | plain | bias)
    prep_all_kernel<<<dim3(4750), blk, 0, stream>>>(
        inputs, Wq, Wk, Wv, Wr, Wo, Wfc, bq, bk, bv, br,
        xin, wall, wall + (size_t)3072 * 512, wot, wfct, ball);

    // fused QKV + residual projection (N=3584), r9 fine 4-phase pipeline
    gemm_qkvr256_kernel<<<dim3(14, 64), dim3(512), 0, stream>>>(
        xin, wall, ball, qc, kb, vt, resf);
    // attention (in place over qc), KVBLK=64 (r11 best)
    mfma_attn_kernel<<<dim3(B_ * HN_ * 4), blk, 0, stream>>>(kb, vt, qc);
    // ln1 = LN1(tanh(qc @ Wo + bo) + resf)   [partner = f32 residual in d_out]
    gemm_ln_kernel<2, false, true><<<dim3(256), dim3(512), 0, stream>>>(
        qc, wot, bo, resf, ln1w, ln1b, ln1, 1024);
    // out = LN2(relu(ln1 @ Wfc + bfc) + ln1)  [f32 final, overwrites d_out]
    gemm_ln_kernel<1, true, false><<<dim3(256), dim3(512), 0, stream>>>(
        ln1, wfct, bfc, ln1, ln2w, ln2b, out, 512);
}